// Round 3
// baseline (883.027 us; speedup 1.0000x reference)
//
#include <hip/hip_runtime.h>
#include <cstdint>
#include <cstddef>
#include <type_traits>

#define N_NODES 50000
#define NRELC   500
#define E1      150000
#define E2N     30000
#define ETOT    180000
#define ALPHA_F 0.2f

__device__ __forceinline__ float bf2f(unsigned short s) {
  return __uint_as_float((unsigned)s << 16);
}
__device__ __forceinline__ unsigned short f2bf(float f) {
  unsigned u = __float_as_uint(f);
  u += 0x7fff + ((u >> 16) & 1);   // round-to-nearest-even
  return (unsigned short)(u >> 16);
}

// ---------------- misc ----------------
__global__ void zero_int(int* __restrict__ p, int n) {
  int i = blockIdx.x * blockDim.x + threadIdx.x;
  if (i < n) p[i] = 0;
}

// ---------------- edge prep ----------------
__global__ void build_edges(const int* __restrict__ el, const int* __restrict__ elnh,
                            int* __restrict__ src, int* __restrict__ dst) {
  int e = blockIdx.x * blockDim.x + threadIdx.x;
  if (e >= ETOT) return;
  if (e < E1) { src[e] = el[e];        dst[e] = el[E1 + e]; }
  else        { int k = e - E1; src[e] = elnh[k]; dst[e] = elnh[E2N + k]; }
}

__global__ void count_edges(const int* __restrict__ src, int* __restrict__ cnt) {
  int e = blockIdx.x * blockDim.x + threadIdx.x;
  if (e < ETOT) atomicAdd(&cnt[src[e]], 1);
}

__global__ void scan_counts(const int* __restrict__ cnt, int* __restrict__ rowptr) {
  __shared__ int lds[1024];
  __shared__ int carry;
  if (threadIdx.x == 0) carry = 0;
  __syncthreads();
  for (int base = 0; base < N_NODES; base += 1024) {
    int i = base + (int)threadIdx.x;
    int v = (i < N_NODES) ? cnt[i] : 0;
    lds[threadIdx.x] = v;
    __syncthreads();
    for (int off = 1; off < 1024; off <<= 1) {
      int t = (threadIdx.x >= (unsigned)off) ? lds[threadIdx.x - off] : 0;
      __syncthreads();
      lds[threadIdx.x] += t;
      __syncthreads();
    }
    int incl = lds[threadIdx.x];
    if (i < N_NODES) rowptr[i] = carry + incl - v;  // exclusive
    __syncthreads();
    if (threadIdx.x == 1023) carry += lds[1023];
    __syncthreads();
  }
  if (threadIdx.x == 0) rowptr[N_NODES] = carry;
}

__global__ void copy_int(const int* __restrict__ a, int* __restrict__ b, int n) {
  int i = blockIdx.x * blockDim.x + threadIdx.x;
  if (i < n) b[i] = a[i];
}

__global__ void fill_csr(const int* __restrict__ src, int* __restrict__ pos, int* __restrict__ csr) {
  int e = blockIdx.x * blockDim.x + threadIdx.x;
  if (e >= ETOT) return;
  int p = atomicAdd(&pos[src[e]], 1);
  csr[p] = e;
}

// ---------------- weight packing ----------------
__global__ void pack_wxa(const float* __restrict__ a, float* __restrict__ o) {
  int i = blockIdx.x * blockDim.x + threadIdx.x;
  if (i >= 512 * 128) return;
  int c = i >> 7, k = i & 127;
  int h = c >> 8, part = (c >> 7) & 1, d = c & 127;
  o[i] = a[h * 49152 + d * 384 + part * 128 + k];
}
__global__ void pack_weea3(const float* __restrict__ a, float* __restrict__ o) {
  int i = blockIdx.x * blockDim.x + threadIdx.x;
  if (i >= 256 * 128) return;
  int c = i >> 7, k = i & 127;
  int h = c >> 7, d = c & 127;
  o[i] = a[h * 49152 + d * 384 + 256 + k];
}
__global__ void pack_wtw(const float* __restrict__ w, float* __restrict__ o) {
  int i = blockIdx.x * blockDim.x + threadIdx.x;
  if (i >= 256 * 128) return;
  int n = i >> 7, k = i & 127;
  o[i] = w[k * 256 + n];
}
__global__ void pack_wx1a(const float* __restrict__ ao, float* __restrict__ o) {
  int i = blockIdx.x * blockDim.x + threadIdx.x;
  if (i >= 512 * 256) return;
  int c = i >> 8, k = i & 255;
  int part = c >> 8, d = c & 255;
  o[i] = ao[d * 768 + part * 256 + k];
}
__global__ void pack_wa3out(const float* __restrict__ ao, float* __restrict__ o) {
  int i = blockIdx.x * blockDim.x + threadIdx.x;
  if (i >= 256 * 256) return;
  int d = i >> 8, k = i & 255;
  o[i] = ao[d * 768 + 512 + k];
}

// ---------------- generic GEMM: C[M,N] = A[M,K] @ Wt[N,K]^T ----------------
// TA/TC: float, or unsigned short (= bf16 storage)
template <typename TA, typename TC>
__global__ __launch_bounds__(256) void gemm_bt(
    const TA* __restrict__ A, const float* __restrict__ Wt,
    TC* __restrict__ C, int M, int N, int K) {
  __shared__ float As[32][132];
  __shared__ float Bs[32][132];
  const int bm = blockIdx.x * 128;
  const int bn = blockIdx.y * 128;
  const int tid = threadIdx.x;
  const int tx = tid & 15;
  const int ty = tid >> 4;
  float acc[8][8];
#pragma unroll
  for (int i = 0; i < 8; ++i)
#pragma unroll
    for (int j = 0; j < 8; ++j) acc[i][j] = 0.f;

  const int lr = tid >> 3;          // 0..31
  const int lc = (tid & 7) << 2;    // 0..28

  for (int k0 = 0; k0 < K; k0 += 32) {
#pragma unroll
    for (int i = 0; i < 4; ++i) {
      const int row = lr + (i << 5);  // 0..127
      float4 av = make_float4(0.f, 0.f, 0.f, 0.f);
      float4 bv = make_float4(0.f, 0.f, 0.f, 0.f);
      const int ga = bm + row, gb = bn + row;
      if (ga < M) {
        if constexpr (std::is_same<TA, float>::value) {
          av = *reinterpret_cast<const float4*>(A + (size_t)ga * K + k0 + lc);
        } else {
          ushort4 t = *reinterpret_cast<const ushort4*>(A + (size_t)ga * K + k0 + lc);
          av = make_float4(bf2f(t.x), bf2f(t.y), bf2f(t.z), bf2f(t.w));
        }
      }
      if (gb < N) bv = *reinterpret_cast<const float4*>(Wt + (size_t)gb * K + k0 + lc);
      As[lc + 0][row] = av.x; As[lc + 1][row] = av.y; As[lc + 2][row] = av.z; As[lc + 3][row] = av.w;
      Bs[lc + 0][row] = bv.x; Bs[lc + 1][row] = bv.y; Bs[lc + 2][row] = bv.z; Bs[lc + 3][row] = bv.w;
    }
    __syncthreads();
    for (int kk = 0; kk < 32; ++kk) {
      float a8[8], b8[8];
      *(float4*)&a8[0] = *(const float4*)&As[kk][ty * 8];
      *(float4*)&a8[4] = *(const float4*)&As[kk][ty * 8 + 4];
      *(float4*)&b8[0] = *(const float4*)&Bs[kk][tx * 8];
      *(float4*)&b8[4] = *(const float4*)&Bs[kk][tx * 8 + 4];
#pragma unroll
      for (int i = 0; i < 8; ++i)
#pragma unroll
        for (int j = 0; j < 8; ++j) acc[i][j] = fmaf(a8[i], b8[j], acc[i][j]);
    }
    __syncthreads();
  }
#pragma unroll
  for (int i = 0; i < 8; ++i) {
    const int gr = bm + ty * 8 + i;
    if (gr < M) {
      if constexpr (std::is_same<TC, float>::value) {
        float4 v0 = make_float4(acc[i][0], acc[i][1], acc[i][2], acc[i][3]);
        float4 v1 = make_float4(acc[i][4], acc[i][5], acc[i][6], acc[i][7]);
        *reinterpret_cast<float4*>(C + (size_t)gr * N + bn + tx * 8) = v0;
        *reinterpret_cast<float4*>(C + (size_t)gr * N + bn + tx * 8 + 4) = v1;
      } else {
        uint4 pk;
        pk.x = (unsigned)f2bf(acc[i][0]) | ((unsigned)f2bf(acc[i][1]) << 16);
        pk.y = (unsigned)f2bf(acc[i][2]) | ((unsigned)f2bf(acc[i][3]) << 16);
        pk.z = (unsigned)f2bf(acc[i][4]) | ((unsigned)f2bf(acc[i][5]) << 16);
        pk.w = (unsigned)f2bf(acc[i][6]) | ((unsigned)f2bf(acc[i][7]) << 16);
        *reinterpret_cast<uint4*>(C + (size_t)gr * N + bn + tx * 8) = pk;
      }
    }
  }
}

// ---------------- layer-1 aggregation: one wave per (node, head) ----------------
__global__ __launch_bounds__(256) void agg1(
    const unsigned short* __restrict__ xa, const unsigned short* __restrict__ eeA31,
    const float* __restrict__ relA3, const int* __restrict__ rowptr,
    const int* __restrict__ csr, const int* __restrict__ dst,
    const int* __restrict__ etnh, const float* __restrict__ a2,
    unsigned short* __restrict__ x1) {
  int w = blockIdx.x * 4 + (threadIdx.x >> 6);
  int n = w >> 1, h = w & 1;
  if (n >= N_NODES) return;
  int l = threadIdx.x & 63;
  float w2a = a2[h * 128 + l];
  float w2b = a2[h * 128 + 64 + l];
  const unsigned short* xan = xa + (size_t)n * 512 + h * 256;
  float s0 = bf2f(xan[l]), s1 = bf2f(xan[64 + l]);
  float acc0 = 0.f, acc1 = 0.f, rs = 0.f;
  int p0 = rowptr[n], p1 = rowptr[n + 1];
  for (int p = p0; p < p1; ++p) {
    int e = csr[p];
    int d = dst[e];
    const unsigned short* xad = xa + (size_t)d * 512 + h * 256 + 128;
    float m0 = s0 + bf2f(xad[l]);
    float m1 = s1 + bf2f(xad[64 + l]);
    if (e < E1) {
      const unsigned short* ee = eeA31 + (size_t)e * 256 + h * 128;
      m0 += bf2f(ee[l]); m1 += bf2f(ee[64 + l]);
    } else {
      int k = e - E1;
      int t0 = etnh[2 * k], t1 = etnh[2 * k + 1];
      const float* r0 = relA3 + t0 * 256 + h * 128;
      const float* r1 = relA3 + t1 * 256 + h * 128;
      m0 += r0[l] + r1[l];
      m1 += r0[64 + l] + r1[64 + l];
    }
    float dot = m0 * w2a + m1 * w2b;
#pragma unroll
    for (int off = 32; off; off >>= 1) dot += __shfl_xor(dot, off);
    float lk = dot > 0.f ? dot : ALPHA_F * dot;
    float ev = __expf(-lk);
    acc0 = fmaf(ev, m0, acc0);
    acc1 = fmaf(ev, m1, acc1);
    rs += ev;
  }
  if (rs == 0.f) rs = 1e-12f;
  float inv = 1.f / rs;
  float h0 = acc0 * inv, h1 = acc1 * inv;
  h0 = h0 > 0.f ? h0 : (__expf(h0) - 1.f);  // elu (concat=True)
  h1 = h1 > 0.f ? h1 : (__expf(h1) - 1.f);
  x1[(size_t)n * 256 + h * 128 + l] = f2bf(h0);
  x1[(size_t)n * 256 + h * 128 + 64 + l] = f2bf(h1);
}

// ---------------- layer-2 aggregation: one wave per node ----------------
__global__ __launch_bounds__(256) void agg2(
    const unsigned short* __restrict__ x1a, const float* __restrict__ rel2,
    const int* __restrict__ rowptr, const int* __restrict__ csr,
    const int* __restrict__ dst, const int* __restrict__ etype,
    const int* __restrict__ etnh, const float* __restrict__ a2o,
    float* __restrict__ out) {
  int n = blockIdx.x * 4 + (threadIdx.x >> 6);
  if (n >= N_NODES) return;
  int l = threadIdx.x & 63;
  float w2[4], s[4], acc[4] = {0.f, 0.f, 0.f, 0.f};
#pragma unroll
  for (int j = 0; j < 4; ++j) {
    w2[j] = a2o[j * 64 + l];
    s[j] = bf2f(x1a[(size_t)n * 512 + j * 64 + l]);
  }
  float rs = 0.f;
  int p0 = rowptr[n], p1 = rowptr[n + 1];
  for (int p = p0; p < p1; ++p) {
    int e = csr[p];
    int d = dst[e];
    const unsigned short* xd = x1a + (size_t)d * 512 + 256;
    float m[4];
    if (e < E1) {
      int t = etype[e];
      const float* r = rel2 + t * 256;
#pragma unroll
      for (int j = 0; j < 4; ++j) m[j] = s[j] + bf2f(xd[j * 64 + l]) + r[j * 64 + l];
    } else {
      int k = e - E1;
      int t0 = etnh[2 * k], t1 = etnh[2 * k + 1];
      const float* r0 = rel2 + t0 * 256;
      const float* r1 = rel2 + t1 * 256;
#pragma unroll
      for (int j = 0; j < 4; ++j) m[j] = s[j] + bf2f(xd[j * 64 + l]) + r0[j * 64 + l] + r1[j * 64 + l];
    }
    float dot = 0.f;
#pragma unroll
    for (int j = 0; j < 4; ++j) dot = fmaf(m[j], w2[j], dot);
#pragma unroll
    for (int off = 32; off; off >>= 1) dot += __shfl_xor(dot, off);
    float lk = dot > 0.f ? dot : ALPHA_F * dot;
    float ev = __expf(-lk);
#pragma unroll
    for (int j = 0; j < 4; ++j) acc[j] = fmaf(ev, m[j], acc[j]);
    rs += ev;
  }
  if (rs == 0.f) rs = 1e-12f;
  float inv = 1.f / rs;
#pragma unroll
  for (int j = 0; j < 4; ++j) {
    float hv = acc[j] * inv;
    hv = hv > 0.f ? hv : (__expf(hv) - 1.f);  // final elu
    out[(size_t)n * 256 + j * 64 + l] = hv;
  }
}

// ---------------- launch ----------------
extern "C" void kernel_launch(void* const* d_in, const int* in_sizes, int n_in,
                              void* d_out, int out_size, void* d_ws, size_t ws_size,
                              hipStream_t stream) {
  const float* x    = (const float*)d_in[0];   // [50000,128]
  const float* rel  = (const float*)d_in[1];   // [500,128]
  const float* eemb = (const float*)d_in[2];   // [150000,128]
  const int*   el   = (const int*)d_in[3];     // [2,150000]
  const int*   et   = (const int*)d_in[4];     // [150000]
  const int*   elnh = (const int*)d_in[5];     // [2,30000]
  const int*   etnh = (const int*)d_in[6];     // [30000,2]
  const float* a    = (const float*)d_in[7];   // [2,128,384]
  const float* a2   = (const float*)d_in[8];   // [2,128]
  const float* W    = (const float*)d_in[9];   // [128,256]
  const float* aout = (const float*)d_in[10];  // [256,768]
  const float* a2o  = (const float*)d_in[11];  // [256]

  char* ws = (char*)d_ws;
  size_t cur = 0;
  auto alloc = [&](size_t bytes) {
    size_t o = cur;
    cur = (cur + bytes + 511) & ~(size_t)511;
    return o;
  };
  int* src     = (int*)(ws + alloc((size_t)ETOT * 4));
  int* dstv    = (int*)(ws + alloc((size_t)ETOT * 4));
  int* rowptr  = (int*)(ws + alloc((size_t)(N_NODES + 1) * 4));
  int* pos     = (int*)(ws + alloc((size_t)N_NODES * 4));
  int* csr     = (int*)(ws + alloc((size_t)ETOT * 4));
  float* wxa   = (float*)(ws + alloc((size_t)512 * 128 * 4));
  float* weea3 = (float*)(ws + alloc((size_t)256 * 128 * 4));
  float* wtw   = (float*)(ws + alloc((size_t)256 * 128 * 4));
  float* wx1a  = (float*)(ws + alloc((size_t)512 * 256 * 4));
  float* wa3o  = (float*)(ws + alloc((size_t)256 * 256 * 4));
  float* relA3 = (float*)(ws + alloc((size_t)NRELC * 256 * 4));
  float* rel2  = (float*)(ws + alloc((size_t)NRELC * 256 * 4));
  // bf16 big intermediates (total ws ~159 MB)
  unsigned short* x1B  = (unsigned short*)(ws + alloc((size_t)N_NODES * 256 * 2));
  unsigned short* xaB  = (unsigned short*)(ws + alloc((size_t)N_NODES * 512 * 2));  // reused as x1a
  unsigned short* eeB  = (unsigned short*)(ws + alloc((size_t)E1 * 256 * 2));
  (void)ws_size; (void)in_sizes; (void)n_in; (void)out_size;

  float* out_x    = (float*)d_out;                       // [50000,256]
  float* out_rel1 = out_x + (size_t)N_NODES * 256;       // [500,256]

  // CSR build (no hipMemsetAsync — zero via kernel)
  zero_int<<<(N_NODES + 255) / 256, 256, 0, stream>>>(pos, N_NODES);
  build_edges<<<(ETOT + 255) / 256, 256, 0, stream>>>(el, elnh, src, dstv);
  count_edges<<<(ETOT + 255) / 256, 256, 0, stream>>>(src, pos);
  scan_counts<<<1, 1024, 0, stream>>>(pos, rowptr);
  copy_int<<<(N_NODES + 255) / 256, 256, 0, stream>>>(rowptr, pos, N_NODES);
  fill_csr<<<(ETOT + 255) / 256, 256, 0, stream>>>(src, pos, csr);

  // weight packs
  pack_wxa<<<(512 * 128 + 255) / 256, 256, 0, stream>>>(a, wxa);
  pack_weea3<<<(256 * 128 + 255) / 256, 256, 0, stream>>>(a, weea3);
  pack_wtw<<<(256 * 128 + 255) / 256, 256, 0, stream>>>(W, wtw);
  pack_wx1a<<<(512 * 256 + 255) / 256, 256, 0, stream>>>(aout, wx1a);
  pack_wa3out<<<(256 * 256 + 255) / 256, 256, 0, stream>>>(aout, wa3o);

  // layer-1 transforms
  gemm_bt<float, unsigned short>
      <<<dim3((N_NODES + 127) / 128, 4), 256, 0, stream>>>(x, wxa, xaB, N_NODES, 512, 128);
  gemm_bt<float, unsigned short>
      <<<dim3((E1 + 127) / 128, 2), 256, 0, stream>>>(eemb, weea3, eeB, E1, 256, 128);
  gemm_bt<float, float>
      <<<dim3((NRELC + 127) / 128, 2), 256, 0, stream>>>(rel, weea3, relA3, NRELC, 256, 128);

  // layer-1 aggregation -> x1
  agg1<<<(N_NODES * 2 + 3) / 4, 256, 0, stream>>>(xaB, eeB, relA3, rowptr, csr, dstv, etnh, a2, x1B);

  // out_relation_1 = rel @ W (direct to output), rel2 table, layer-2 transform
  gemm_bt<float, float>
      <<<dim3((NRELC + 127) / 128, 2), 256, 0, stream>>>(rel, wtw, out_rel1, NRELC, 256, 128);
  gemm_bt<float, float>
      <<<dim3((NRELC + 127) / 128, 2), 256, 0, stream>>>(out_rel1, wa3o, rel2, NRELC, 256, 256);
  gemm_bt<unsigned short, unsigned short>
      <<<dim3((N_NODES + 127) / 128, 4), 256, 0, stream>>>(x1B, wx1a, xaB, N_NODES, 512, 256);

  // layer-2 aggregation -> final x
  agg2<<<(N_NODES + 3) / 4, 256, 0, stream>>>(xaB, rel2, rowptr, csr, dstv, et, etnh, a2o, out_x);
}

// Round 5
// 611.859 us; speedup vs baseline: 1.4432x; 1.4432x over previous
//
#include <hip/hip_runtime.h>
#include <cstdint>
#include <cstddef>

#define N_NODES 50000
#define MP1     50048     // N_NODES padded to 128
#define NRELC   500
#define E1      150000
#define MP2     150016    // E1 padded to 128
#define E2N     30000
#define ETOT    180000
#define ALPHA_F 0.2f

typedef __attribute__((ext_vector_type(8))) short bf16x8;   // 8 bf16 (4 VGPRs)
typedef __attribute__((ext_vector_type(4))) float f32x4;

__device__ __forceinline__ float bf2f(unsigned short s) {
  return __uint_as_float((unsigned)s << 16);
}
__device__ __forceinline__ unsigned short f2bf(float f) {
  unsigned u = __float_as_uint(f);
  u += 0x7fff + ((u >> 16) & 1);   // round-to-nearest-even
  return (unsigned short)(u >> 16);
}

// ---------------- misc ----------------
__global__ void zero_int(int* __restrict__ p, int n) {
  int i = blockIdx.x * blockDim.x + threadIdx.x;
  if (i < n) p[i] = 0;
}

// ---------------- edge prep ----------------
__global__ void build_edges(const int* __restrict__ el, const int* __restrict__ elnh,
                            int* __restrict__ src, int* __restrict__ dst) {
  int e = blockIdx.x * blockDim.x + threadIdx.x;
  if (e >= ETOT) return;
  if (e < E1) { src[e] = el[e];        dst[e] = el[E1 + e]; }
  else        { int k = e - E1; src[e] = elnh[k]; dst[e] = elnh[E2N + k]; }
}

__global__ void count_edges(const int* __restrict__ src, int* __restrict__ cnt) {
  int e = blockIdx.x * blockDim.x + threadIdx.x;
  if (e < ETOT) atomicAdd(&cnt[src[e]], 1);
}

__global__ void scan_counts(const int* __restrict__ cnt, int* __restrict__ rowptr) {
  __shared__ int lds[1024];
  __shared__ int carry;
  if (threadIdx.x == 0) carry = 0;
  __syncthreads();
  for (int base = 0; base < N_NODES; base += 1024) {
    int i = base + (int)threadIdx.x;
    int v = (i < N_NODES) ? cnt[i] : 0;
    lds[threadIdx.x] = v;
    __syncthreads();
    for (int off = 1; off < 1024; off <<= 1) {
      int t = (threadIdx.x >= (unsigned)off) ? lds[threadIdx.x - off] : 0;
      __syncthreads();
      lds[threadIdx.x] += t;
      __syncthreads();
    }
    int incl = lds[threadIdx.x];
    if (i < N_NODES) rowptr[i] = carry + incl - v;  // exclusive
    __syncthreads();
    if (threadIdx.x == 1023) carry += lds[1023];
    __syncthreads();
  }
  if (threadIdx.x == 0) rowptr[N_NODES] = carry;
}

__global__ void copy_int(const int* __restrict__ a, int* __restrict__ b, int n) {
  int i = blockIdx.x * blockDim.x + threadIdx.x;
  if (i < n) b[i] = a[i];
}

__global__ void fill_csr(const int* __restrict__ src, int* __restrict__ pos, int* __restrict__ csr) {
  int e = blockIdx.x * blockDim.x + threadIdx.x;
  if (e >= ETOT) return;
  int p = atomicAdd(&pos[src[e]], 1);
  csr[p] = e;
}

// ---------------- weight packing ----------------
// f32 packs (for small NRELC gemms)
__global__ void pack_weea3(const float* __restrict__ a, float* __restrict__ o) {
  int i = blockIdx.x * blockDim.x + threadIdx.x;
  if (i >= 256 * 128) return;
  int c = i >> 7, k = i & 127;
  int h = c >> 7, d = c & 127;
  o[i] = a[h * 49152 + d * 384 + 256 + k];
}
__global__ void pack_wtw(const float* __restrict__ w, float* __restrict__ o) {
  int i = blockIdx.x * blockDim.x + threadIdx.x;
  if (i >= 256 * 128) return;
  int n = i >> 7, k = i & 127;
  o[i] = w[k * 256 + n];
}
__global__ void pack_wa3out(const float* __restrict__ ao, float* __restrict__ o) {
  int i = blockIdx.x * blockDim.x + threadIdx.x;
  if (i >= 256 * 256) return;
  int d = i >> 8, k = i & 255;
  o[i] = ao[d * 768 + 512 + k];
}
// bf16 packs (for MFMA gemms)
__global__ void pack_wxa_bf(const float* __restrict__ a, unsigned short* __restrict__ o) {
  int i = blockIdx.x * blockDim.x + threadIdx.x;
  if (i >= 512 * 128) return;
  int c = i >> 7, k = i & 127;
  int h = c >> 8, part = (c >> 7) & 1, d = c & 127;
  o[i] = f2bf(a[h * 49152 + d * 384 + part * 128 + k]);
}
__global__ void pack_weea3_bf(const float* __restrict__ a, unsigned short* __restrict__ o) {
  int i = blockIdx.x * blockDim.x + threadIdx.x;
  if (i >= 256 * 128) return;
  int c = i >> 7, k = i & 127;
  int h = c >> 7, d = c & 127;
  o[i] = f2bf(a[h * 49152 + d * 384 + 256 + k]);
}
__global__ void pack_wx1a_bf(const float* __restrict__ ao, unsigned short* __restrict__ o) {
  int i = blockIdx.x * blockDim.x + threadIdx.x;
  if (i >= 512 * 256) return;
  int c = i >> 8, k = i & 255;
  int part = c >> 8, d = c & 255;
  o[i] = f2bf(ao[d * 768 + part * 256 + k]);
}

// ---------------- small f32 GEMM: C[M,N] = A[M,K] @ Wt[N,K]^T ----------------
__global__ __launch_bounds__(256) void gemm_bt_f32(
    const float* __restrict__ A, const float* __restrict__ Wt,
    float* __restrict__ C, int M, int N, int K) {
  __shared__ float As[32][132];
  __shared__ float Bs[32][132];
  const int bm = blockIdx.x * 128;
  const int bn = blockIdx.y * 128;
  const int tid = threadIdx.x;
  const int tx = tid & 15;
  const int ty = tid >> 4;
  float acc[8][8];
#pragma unroll
  for (int i = 0; i < 8; ++i)
#pragma unroll
    for (int j = 0; j < 8; ++j) acc[i][j] = 0.f;

  const int lr = tid >> 3;
  const int lc = (tid & 7) << 2;

  for (int k0 = 0; k0 < K; k0 += 32) {
#pragma unroll
    for (int i = 0; i < 4; ++i) {
      const int row = lr + (i << 5);
      float4 av = make_float4(0.f, 0.f, 0.f, 0.f);
      float4 bv = make_float4(0.f, 0.f, 0.f, 0.f);
      const int ga = bm + row, gb = bn + row;
      if (ga < M) av = *reinterpret_cast<const float4*>(A + (size_t)ga * K + k0 + lc);
      if (gb < N) bv = *reinterpret_cast<const float4*>(Wt + (size_t)gb * K + k0 + lc);
      As[lc + 0][row] = av.x; As[lc + 1][row] = av.y; As[lc + 2][row] = av.z; As[lc + 3][row] = av.w;
      Bs[lc + 0][row] = bv.x; Bs[lc + 1][row] = bv.y; Bs[lc + 2][row] = bv.z; Bs[lc + 3][row] = bv.w;
    }
    __syncthreads();
    for (int kk = 0; kk < 32; ++kk) {
      float a8[8], b8[8];
      *(float4*)&a8[0] = *(const float4*)&As[kk][ty * 8];
      *(float4*)&a8[4] = *(const float4*)&As[kk][ty * 8 + 4];
      *(float4*)&b8[0] = *(const float4*)&Bs[kk][tx * 8];
      *(float4*)&b8[4] = *(const float4*)&Bs[kk][tx * 8 + 4];
#pragma unroll
      for (int i = 0; i < 8; ++i)
#pragma unroll
        for (int j = 0; j < 8; ++j) acc[i][j] = fmaf(a8[i], b8[j], acc[i][j]);
    }
    __syncthreads();
  }
#pragma unroll
  for (int i = 0; i < 8; ++i) {
    const int gr = bm + ty * 8 + i;
    if (gr < M) {
      float4 v0 = make_float4(acc[i][0], acc[i][1], acc[i][2], acc[i][3]);
      float4 v1 = make_float4(acc[i][4], acc[i][5], acc[i][6], acc[i][7]);
      *reinterpret_cast<float4*>(C + (size_t)gr * N + bn + tx * 8) = v0;
      *reinterpret_cast<float4*>(C + (size_t)gr * N + bn + tx * 8 + 4) = v1;
    }
  }
}

// ---------------- MFMA bf16 GEMM: C[Mpad,N](bf16) = A[Mpad,K] @ Wt[N,K]^T ----------------
// TA = float  -> reg-stage + cvt (global loads guarded by Mreal, zeros beyond)
// TA = ushort -> global_load_lds direct (A must be padded to Mpad rows)
// LDS XOR-swizzle: physical byte chunk pc holds logical byte chunk pc ^ ((row&3)<<4)
// (involution; applied on global SOURCE for staging and on the frag-read address)
template <typename TA, int K>
__global__ __launch_bounds__(256) void gemm_mfma(
    const TA* __restrict__ A, const unsigned short* __restrict__ Wt,
    unsigned short* __restrict__ C, int Mreal, int N) {
  __shared__ __align__(16) unsigned short lds[2][8192];  // per buf: A[0..4095], B[4096..8191] ([128][32] bf16 each)
  const int tid  = threadIdx.x;
  const int wave = tid >> 6;
  const int lane = tid & 63;
  const int bm = blockIdx.x * 128;
  const int bn = blockIdx.y * 128;
  const int wr = wave >> 1, wc = wave & 1;     // wave sub-tile 64x64
  constexpr int NT = K / 32;

  f32x4 acc[4][4] = {};

  const int rb   = lane & 15;
  const int cofs = ((lane >> 4) ^ (lane & 3)) << 3;   // swizzled k-chunk, ushort offset

  auto stageB = [&](int buf, int kt) {
#pragma unroll
    for (int j = 0; j < 2; ++j) {
      const int o   = (wave * 2 + j) * 1024 + lane * 16;  // physical byte offset in tile
      const int row = o >> 6;
      const int sc  = (o & 63) ^ ((row & 3) << 4);
      const char* g = (const char*)Wt + (size_t)(bn + row) * (K * 2) + kt * 64 + sc;
      // LDS dest: wave-uniform base; HW adds lane*16
      __builtin_amdgcn_global_load_lds(
          (const __attribute__((address_space(1))) void*)g,
          (__attribute__((address_space(3))) void*)&lds[buf][4096 + (wave * 2 + j) * 512],
          16, 0, 0);
    }
  };
  auto stageA = [&](int buf, int kt) {
    if constexpr (sizeof(TA) == 2) {
#pragma unroll
      for (int j = 0; j < 2; ++j) {
        const int o   = (wave * 2 + j) * 1024 + lane * 16;
        const int row = o >> 6;
        const int sc  = (o & 63) ^ ((row & 3) << 4);
        const char* g = (const char*)A + (size_t)(bm + row) * (K * 2) + kt * 64 + sc;
        __builtin_amdgcn_global_load_lds(
            (const __attribute__((address_space(1))) void*)g,
            (__attribute__((address_space(3))) void*)&lds[buf][(wave * 2 + j) * 512],
            16, 0, 0);
      }
    } else {
#pragma unroll
      for (int p = 0; p < 2; ++p) {
        const int o   = p * 4096 + tid * 16;
        const int row = o >> 6;
        const int ke  = ((o & 63) ^ ((row & 3) << 4)) >> 1;  // logical bf16 elem offset (mult of 8)
        const int gr  = bm + row;
        float v[8];
#pragma unroll
        for (int q = 0; q < 8; ++q) v[q] = 0.f;
        if (gr < Mreal) {
          const float* gp = (const float*)A + (size_t)gr * K + kt * 32 + ke;
          float4 u0 = *(const float4*)gp;
          float4 u1 = *(const float4*)(gp + 4);
          v[0] = u0.x; v[1] = u0.y; v[2] = u0.z; v[3] = u0.w;
          v[4] = u1.x; v[5] = u1.y; v[6] = u1.z; v[7] = u1.w;
        }
        bf16x8 pk;
#pragma unroll
        for (int q = 0; q < 8; ++q) pk[q] = (short)f2bf(v[q]);
        *(bf16x8*)&lds[buf][o >> 1] = pk;
      }
    }
  };

  stageA(0, 0); stageB(0, 0);
  for (int t = 0; t < NT; ++t) {
    __syncthreads();                       // drains vmcnt+lgkm of stage(t)
    if (t + 1 < NT) { stageA((t + 1) & 1, t + 1); stageB((t + 1) & 1, t + 1); }
    const int buf = t & 1;
    bf16x8 af[4], bfr[4];
#pragma unroll
    for (int m = 0; m < 4; ++m)
      af[m] = *(const bf16x8*)&lds[buf][(rb + 16 * m + 64 * wr) * 32 + cofs];
#pragma unroll
    for (int n = 0; n < 4; ++n)
      bfr[n] = *(const bf16x8*)&lds[buf][4096 + (rb + 16 * n + 64 * wc) * 32 + cofs];
#pragma unroll
    for (int m = 0; m < 4; ++m)
#pragma unroll
      for (int n = 0; n < 4; ++n)
        acc[m][n] = __builtin_amdgcn_mfma_f32_16x16x32_bf16(af[m], bfr[n], acc[m][n], 0, 0, 0);
  }

  // C/D layout: col = lane&15, row = (lane>>4)*4 + reg   [m89 verified]
  const int ccol = bn + wc * 64 + rb;
  const int crow = bm + wr * 64 + ((lane >> 4) << 2);
#pragma unroll
  for (int m = 0; m < 4; ++m)
#pragma unroll
    for (int n = 0; n < 4; ++n)
#pragma unroll
      for (int r = 0; r < 4; ++r)
        C[(size_t)(crow + 16 * m + r) * N + ccol + 16 * n] = f2bf(acc[m][n][r]);
}

// ---------------- layer-1 aggregation: one wave per (node, head) ----------------
__global__ __launch_bounds__(256) void agg1(
    const unsigned short* __restrict__ xa, const unsigned short* __restrict__ eeA31,
    const float* __restrict__ relA3, const int* __restrict__ rowptr,
    const int* __restrict__ csr, const int* __restrict__ dst,
    const int* __restrict__ etnh, const float* __restrict__ a2,
    unsigned short* __restrict__ x1) {
  int w = blockIdx.x * 4 + (threadIdx.x >> 6);
  int n = w >> 1, h = w & 1;
  if (n >= N_NODES) return;
  int l = threadIdx.x & 63;
  float w2a = a2[h * 128 + l];
  float w2b = a2[h * 128 + 64 + l];
  const unsigned short* xan = xa + (size_t)n * 512 + h * 256;
  float s0 = bf2f(xan[l]), s1 = bf2f(xan[64 + l]);
  float acc0 = 0.f, acc1 = 0.f, rs = 0.f;
  int p0 = rowptr[n], p1 = rowptr[n + 1];
  for (int p = p0; p < p1; ++p) {
    int e = csr[p];
    int d = dst[e];
    const unsigned short* xad = xa + (size_t)d * 512 + h * 256 + 128;
    float m0 = s0 + bf2f(xad[l]);
    float m1 = s1 + bf2f(xad[64 + l]);
    if (e < E1) {
      const unsigned short* ee = eeA31 + (size_t)e * 256 + h * 128;
      m0 += bf2f(ee[l]); m1 += bf2f(ee[64 + l]);
    } else {
      int k = e - E1;
      int t0 = etnh[2 * k], t1 = etnh[2 * k + 1];
      const float* r0 = relA3 + t0 * 256 + h * 128;
      const float* r1 = relA3 + t1 * 256 + h * 128;
      m0 += r0[l] + r1[l];
      m1 += r0[64 + l] + r1[64 + l];
    }
    float dot = m0 * w2a + m1 * w2b;
#pragma unroll
    for (int off = 32; off; off >>= 1) dot += __shfl_xor(dot, off);
    float lk = dot > 0.f ? dot : ALPHA_F * dot;
    float ev = __expf(-lk);
    acc0 = fmaf(ev, m0, acc0);
    acc1 = fmaf(ev, m1, acc1);
    rs += ev;
  }
  if (rs == 0.f) rs = 1e-12f;
  float inv = 1.f / rs;
  float h0 = acc0 * inv, h1 = acc1 * inv;
  h0 = h0 > 0.f ? h0 : (__expf(h0) - 1.f);  // elu (concat=True)
  h1 = h1 > 0.f ? h1 : (__expf(h1) - 1.f);
  x1[(size_t)n * 256 + h * 128 + l] = f2bf(h0);
  x1[(size_t)n * 256 + h * 128 + 64 + l] = f2bf(h1);
}

// ---------------- layer-2 aggregation: one wave per node ----------------
__global__ __launch_bounds__(256) void agg2(
    const unsigned short* __restrict__ x1a, const float* __restrict__ rel2,
    const int* __restrict__ rowptr, const int* __restrict__ csr,
    const int* __restrict__ dst, const int* __restrict__ etype,
    const int* __restrict__ etnh, const float* __restrict__ a2o,
    float* __restrict__ out) {
  int n = blockIdx.x * 4 + (threadIdx.x >> 6);
  if (n >= N_NODES) return;
  int l = threadIdx.x & 63;
  float w2[4], s[4], acc[4] = {0.f, 0.f, 0.f, 0.f};
#pragma unroll
  for (int j = 0; j < 4; ++j) {
    w2[j] = a2o[j * 64 + l];
    s[j] = bf2f(x1a[(size_t)n * 512 + j * 64 + l]);
  }
  float rs = 0.f;
  int p0 = rowptr[n], p1 = rowptr[n + 1];
  for (int p = p0; p < p1; ++p) {
    int e = csr[p];
    int d = dst[e];
    const unsigned short* xd = x1a + (size_t)d * 512 + 256;
    float m[4];
    if (e < E1) {
      int t = etype[e];
      const float* r = rel2 + t * 256;
#pragma unroll
      for (int j = 0; j < 4; ++j) m[j] = s[j] + bf2f(xd[j * 64 + l]) + r[j * 64 + l];
    } else {
      int k = e - E1;
      int t0 = etnh[2 * k], t1 = etnh[2 * k + 1];
      const float* r0 = rel2 + t0 * 256;
      const float* r1 = rel2 + t1 * 256;
#pragma unroll
      for (int j = 0; j < 4; ++j) m[j] = s[j] + bf2f(xd[j * 64 + l]) + r0[j * 64 + l] + r1[j * 64 + l];
    }
    float dot = 0.f;
#pragma unroll
    for (int j = 0; j < 4; ++j) dot = fmaf(m[j], w2[j], dot);
#pragma unroll
    for (int off = 32; off; off >>= 1) dot += __shfl_xor(dot, off);
    float lk = dot > 0.f ? dot : ALPHA_F * dot;
    float ev = __expf(-lk);
#pragma unroll
    for (int j = 0; j < 4; ++j) acc[j] = fmaf(ev, m[j], acc[j]);
    rs += ev;
  }
  if (rs == 0.f) rs = 1e-12f;
  float inv = 1.f / rs;
#pragma unroll
  for (int j = 0; j < 4; ++j) {
    float hv = acc[j] * inv;
    hv = hv > 0.f ? hv : (__expf(hv) - 1.f);  // final elu
    out[(size_t)n * 256 + j * 64 + l] = hv;
  }
}

// ---------------- launch ----------------
extern "C" void kernel_launch(void* const* d_in, const int* in_sizes, int n_in,
                              void* d_out, int out_size, void* d_ws, size_t ws_size,
                              hipStream_t stream) {
  const float* x    = (const float*)d_in[0];   // [50000,128]
  const float* rel  = (const float*)d_in[1];   // [500,128]
  const float* eemb = (const float*)d_in[2];   // [150000,128]
  const int*   el   = (const int*)d_in[3];     // [2,150000]
  const int*   et   = (const int*)d_in[4];     // [150000]
  const int*   elnh = (const int*)d_in[5];     // [2,30000]
  const int*   etnh = (const int*)d_in[6];     // [30000,2]
  const float* a    = (const float*)d_in[7];   // [2,128,384]
  const float* a2   = (const float*)d_in[8];   // [2,128]
  const float* W    = (const float*)d_in[9];   // [128,256]
  const float* aout = (const float*)d_in[10];  // [256,768]
  const float* a2o  = (const float*)d_in[11];  // [256]

  char* ws = (char*)d_ws;
  size_t cur = 0;
  auto alloc = [&](size_t bytes) {
    size_t o = cur;
    cur = (cur + bytes + 511) & ~(size_t)511;
    return o;
  };
  int* src     = (int*)(ws + alloc((size_t)ETOT * 4));
  int* dstv    = (int*)(ws + alloc((size_t)ETOT * 4));
  int* rowptr  = (int*)(ws + alloc((size_t)(N_NODES + 1) * 4));
  int* pos     = (int*)(ws + alloc((size_t)N_NODES * 4));
  int* csr     = (int*)(ws + alloc((size_t)ETOT * 4));
  float* weea3f = (float*)(ws + alloc((size_t)256 * 128 * 4));
  float* wtw    = (float*)(ws + alloc((size_t)256 * 128 * 4));
  float* wa3o   = (float*)(ws + alloc((size_t)256 * 256 * 4));
  unsigned short* wxa_bf   = (unsigned short*)(ws + alloc((size_t)512 * 128 * 2));
  unsigned short* weea3_bf = (unsigned short*)(ws + alloc((size_t)256 * 128 * 2));
  unsigned short* wx1a_bf  = (unsigned short*)(ws + alloc((size_t)512 * 256 * 2));
  float* relA3 = (float*)(ws + alloc((size_t)NRELC * 256 * 4));
  float* rel2  = (float*)(ws + alloc((size_t)NRELC * 256 * 4));
  unsigned short* x1B = (unsigned short*)(ws + alloc((size_t)MP1 * 256 * 2));  // 25.6MB (padded)
  unsigned short* xaB = (unsigned short*)(ws + alloc((size_t)MP1 * 512 * 2));  // 51.2MB (padded; reused as x1a)
  unsigned short* eeB = (unsigned short*)(ws + alloc((size_t)MP2 * 256 * 2));  // 76.8MB (padded)
  (void)ws_size; (void)in_sizes; (void)n_in; (void)out_size;

  float* out_x    = (float*)d_out;                       // [50000,256]
  float* out_rel1 = out_x + (size_t)N_NODES * 256;       // [500,256]

  // CSR build
  zero_int<<<(N_NODES + 255) / 256, 256, 0, stream>>>(pos, N_NODES);
  build_edges<<<(ETOT + 255) / 256, 256, 0, stream>>>(el, elnh, src, dstv);
  count_edges<<<(ETOT + 255) / 256, 256, 0, stream>>>(src, pos);
  scan_counts<<<1, 1024, 0, stream>>>(pos, rowptr);
  copy_int<<<(N_NODES + 255) / 256, 256, 0, stream>>>(rowptr, pos, N_NODES);
  fill_csr<<<(ETOT + 255) / 256, 256, 0, stream>>>(src, pos, csr);

  // weight packs
  pack_weea3<<<(256 * 128 + 255) / 256, 256, 0, stream>>>(a, weea3f);
  pack_wtw<<<(256 * 128 + 255) / 256, 256, 0, stream>>>(W, wtw);
  pack_wa3out<<<(256 * 256 + 255) / 256, 256, 0, stream>>>(aout, wa3o);
  pack_wxa_bf<<<(512 * 128 + 255) / 256, 256, 0, stream>>>(a, wxa_bf);
  pack_weea3_bf<<<(256 * 128 + 255) / 256, 256, 0, stream>>>(a, weea3_bf);
  pack_wx1a_bf<<<(512 * 256 + 255) / 256, 256, 0, stream>>>(aout, wx1a_bf);

  // layer-1 transforms (MFMA)
  gemm_mfma<float, 128><<<dim3(MP1 / 128, 4), 256, 0, stream>>>(x, wxa_bf, xaB, N_NODES, 512);
  gemm_mfma<float, 128><<<dim3(MP2 / 128, 2), 256, 0, stream>>>(eemb, weea3_bf, eeB, E1, 256);
  gemm_bt_f32<<<dim3((NRELC + 127) / 128, 2), 256, 0, stream>>>(rel, weea3f, relA3, NRELC, 256, 128);

  // layer-1 aggregation -> x1
  agg1<<<(N_NODES * 2 + 3) / 4, 256, 0, stream>>>(xaB, eeB, relA3, rowptr, csr, dstv, etnh, a2, x1B);

  // out_relation_1 = rel @ W (direct to output), rel2 table
  gemm_bt_f32<<<dim3((NRELC + 127) / 128, 2), 256, 0, stream>>>(rel, wtw, out_rel1, NRELC, 256, 128);
  gemm_bt_f32<<<dim3((NRELC + 127) / 128, 2), 256, 0, stream>>>(out_rel1, wa3o, rel2, NRELC, 256, 256);

  // layer-2 transform (MFMA, A = x1B bf16 padded)
  gemm_mfma<unsigned short, 256><<<dim3(MP1 / 128, 4), 256, 0, stream>>>(x1B, wx1a_bf, xaB, MP1, 512);

  // layer-2 aggregation -> final x
  agg2<<<(N_NODES + 3) / 4, 256, 0, stream>>>(xaB, rel2, rowptr, csr, dstv, et, etnh, a2o, out_x);
}

// Round 6
// 496.449 us; speedup vs baseline: 1.7787x; 1.2325x over previous
//
#include <hip/hip_runtime.h>
#include <cstdint>
#include <cstddef>

#define N_NODES 50000
#define MP1     50048     // N_NODES padded to 128
#define NRELC   500
#define E1      150000
#define MP2     150016    // E1 padded to 128
#define E2N     30000
#define ETOT    180000
#define ALPHA_F 0.2f
#define NBSCAN  49        // ceil(N_NODES / 1024)

typedef __attribute__((ext_vector_type(8))) short bf16x8;   // 8 bf16 (4 VGPRs)
typedef __attribute__((ext_vector_type(4))) float f32x4;

__device__ __forceinline__ float bf2f(unsigned short s) {
  return __uint_as_float((unsigned)s << 16);
}
__device__ __forceinline__ unsigned short f2bf(float f) {
  unsigned u = __float_as_uint(f);
  u += 0x7fff + ((u >> 16) & 1);   // round-to-nearest-even
  return (unsigned short)(u >> 16);
}

// ---------------- misc ----------------
__global__ void zero_int(int* __restrict__ p, int n) {
  int i = blockIdx.x * blockDim.x + threadIdx.x;
  if (i < n) p[i] = 0;
}

// ---------------- edge prep (fused build + count) ----------------
__global__ void build_count(const int* __restrict__ el, const int* __restrict__ elnh,
                            int* __restrict__ src, int* __restrict__ dst,
                            int* __restrict__ cnt) {
  int e = blockIdx.x * blockDim.x + threadIdx.x;
  if (e >= ETOT) return;
  int s, d;
  if (e < E1) { s = el[e];  d = el[E1 + e]; }
  else        { int k = e - E1; s = elnh[k]; d = elnh[E2N + k]; }
  src[e] = s; dst[e] = d;
  atomicAdd(&cnt[s], 1);
}

// ---------------- hierarchical exclusive scan over cnt[N_NODES] ----------------
// stage 1: per-block (1024 elems) local exclusive scan -> rowptr, block total -> blocksum
__global__ __launch_bounds__(256) void block_scan(const int* __restrict__ cnt,
                                                  int* __restrict__ rowptr,
                                                  int* __restrict__ blocksum) {
  __shared__ int wsum[4];
  const int tid  = threadIdx.x;
  const int lane = tid & 63;
  const int wave = tid >> 6;
  const int idx  = blockIdx.x * 1024 + tid * 4;
  int v0 = 0, v1 = 0, v2 = 0, v3 = 0;
  if (idx + 3 < N_NODES) {
    int4 t = *reinterpret_cast<const int4*>(cnt + idx);
    v0 = t.x; v1 = t.y; v2 = t.z; v3 = t.w;
  } else {
    if (idx + 0 < N_NODES) v0 = cnt[idx + 0];
    if (idx + 1 < N_NODES) v1 = cnt[idx + 1];
    if (idx + 2 < N_NODES) v2 = cnt[idx + 2];
  }
  const int tsum = v0 + v1 + v2 + v3;
  int incl = tsum;
#pragma unroll
  for (int off = 1; off < 64; off <<= 1) {
    int u = __shfl_up(incl, off);
    if (lane >= off) incl += u;
  }
  if (lane == 63) wsum[wave] = incl;
  __syncthreads();
  int woff = 0;
#pragma unroll
  for (int w = 0; w < 4; ++w)
    if (w < wave) woff += wsum[w];
  const int ebase = woff + incl - tsum;  // exclusive base for this thread
  if (idx + 0 < N_NODES) rowptr[idx + 0] = ebase;
  if (idx + 1 < N_NODES) rowptr[idx + 1] = ebase + v0;
  if (idx + 2 < N_NODES) rowptr[idx + 2] = ebase + v0 + v1;
  if (idx + 3 < N_NODES) rowptr[idx + 3] = ebase + v0 + v1 + v2;
  if (tid == 255) blocksum[blockIdx.x] = woff + incl;  // block total
}

// stage 2: scan the NBSCAN block sums (single wave); write grand total to rowptr[N]
__global__ void scan_blocksums(int* __restrict__ blocksum, int* __restrict__ rowptr) {
  const int lane = threadIdx.x & 63;
  int v = (lane < NBSCAN) ? blocksum[lane] : 0;
  int incl = v;
#pragma unroll
  for (int off = 1; off < 64; off <<= 1) {
    int u = __shfl_up(incl, off);
    if (lane >= off) incl += u;
  }
  if (lane < NBSCAN) blocksum[lane] = incl - v;  // exclusive
  if (lane == 63) rowptr[N_NODES] = incl;        // total (= ETOT)
}

// stage 3: add block offsets; also produce pos copy for fill_csr
__global__ void add_offsets(int* __restrict__ rowptr, const int* __restrict__ blocksum,
                            int* __restrict__ pos) {
  int i = blockIdx.x * 256 + threadIdx.x;
  if (i < N_NODES) {
    int r = rowptr[i] + blocksum[i >> 10];
    rowptr[i] = r;
    pos[i] = r;
  }
}

__global__ void fill_csr(const int* __restrict__ src, int* __restrict__ pos, int* __restrict__ csr) {
  int e = blockIdx.x * blockDim.x + threadIdx.x;
  if (e >= ETOT) return;
  int p = atomicAdd(&pos[src[e]], 1);
  csr[p] = e;
}

// ---------------- fused weight packing ----------------
// ranges (in order): weea3f 32768 | wtw 32768 | wa3o 65536 | wxa_bf 65536 | weea3_bf 32768 | wx1a_bf 131072
#define PK_TOT (32768 + 32768 + 65536 + 65536 + 32768 + 131072)
__global__ void pack_all(const float* __restrict__ a, const float* __restrict__ W,
                         const float* __restrict__ ao,
                         float* __restrict__ weea3f, float* __restrict__ wtw,
                         float* __restrict__ wa3o,
                         unsigned short* __restrict__ wxa_bf,
                         unsigned short* __restrict__ weea3_bf,
                         unsigned short* __restrict__ wx1a_bf) {
  int i = blockIdx.x * blockDim.x + threadIdx.x;
  if (i >= PK_TOT) return;
  if (i < 32768) {
    int c = i >> 7, k = i & 127;
    int h = c >> 7, d = c & 127;
    weea3f[i] = a[h * 49152 + d * 384 + 256 + k];
  } else if (i < 65536) {
    int j = i - 32768;
    int n = j >> 7, k = j & 127;
    wtw[j] = W[k * 256 + n];
  } else if (i < 131072) {
    int j = i - 65536;
    int d = j >> 8, k = j & 255;
    wa3o[j] = ao[d * 768 + 512 + k];
  } else if (i < 196608) {
    int j = i - 131072;
    int c = j >> 7, k = j & 127;
    int h = c >> 8, part = (c >> 7) & 1, d = c & 127;
    wxa_bf[j] = f2bf(a[h * 49152 + d * 384 + part * 128 + k]);
  } else if (i < 229376) {
    int j = i - 196608;
    int c = j >> 7, k = j & 127;
    int h = c >> 7, d = c & 127;
    weea3_bf[j] = f2bf(a[h * 49152 + d * 384 + 256 + k]);
  } else {
    int j = i - 229376;
    int c = j >> 8, k = j & 255;
    int part = c >> 8, d = c & 255;
    wx1a_bf[j] = f2bf(ao[d * 768 + part * 256 + k]);
  }
}

// ---------------- small f32 GEMM: C[M,N] = A[M,K] @ Wt[N,K]^T ----------------
__global__ __launch_bounds__(256) void gemm_bt_f32(
    const float* __restrict__ A, const float* __restrict__ Wt,
    float* __restrict__ C, int M, int N, int K) {
  __shared__ float As[32][132];
  __shared__ float Bs[32][132];
  const int bm = blockIdx.x * 128;
  const int bn = blockIdx.y * 128;
  const int tid = threadIdx.x;
  const int tx = tid & 15;
  const int ty = tid >> 4;
  float acc[8][8];
#pragma unroll
  for (int i = 0; i < 8; ++i)
#pragma unroll
    for (int j = 0; j < 8; ++j) acc[i][j] = 0.f;

  const int lr = tid >> 3;
  const int lc = (tid & 7) << 2;

  for (int k0 = 0; k0 < K; k0 += 32) {
#pragma unroll
    for (int i = 0; i < 4; ++i) {
      const int row = lr + (i << 5);
      float4 av = make_float4(0.f, 0.f, 0.f, 0.f);
      float4 bv = make_float4(0.f, 0.f, 0.f, 0.f);
      const int ga = bm + row, gb = bn + row;
      if (ga < M) av = *reinterpret_cast<const float4*>(A + (size_t)ga * K + k0 + lc);
      if (gb < N) bv = *reinterpret_cast<const float4*>(Wt + (size_t)gb * K + k0 + lc);
      As[lc + 0][row] = av.x; As[lc + 1][row] = av.y; As[lc + 2][row] = av.z; As[lc + 3][row] = av.w;
      Bs[lc + 0][row] = bv.x; Bs[lc + 1][row] = bv.y; Bs[lc + 2][row] = bv.z; Bs[lc + 3][row] = bv.w;
    }
    __syncthreads();
    for (int kk = 0; kk < 32; ++kk) {
      float a8[8], b8[8];
      *(float4*)&a8[0] = *(const float4*)&As[kk][ty * 8];
      *(float4*)&a8[4] = *(const float4*)&As[kk][ty * 8 + 4];
      *(float4*)&b8[0] = *(const float4*)&Bs[kk][tx * 8];
      *(float4*)&b8[4] = *(const float4*)&Bs[kk][tx * 8 + 4];
#pragma unroll
      for (int i = 0; i < 8; ++i)
#pragma unroll
        for (int j = 0; j < 8; ++j) acc[i][j] = fmaf(a8[i], b8[j], acc[i][j]);
    }
    __syncthreads();
  }
#pragma unroll
  for (int i = 0; i < 8; ++i) {
    const int gr = bm + ty * 8 + i;
    if (gr < M) {
      float4 v0 = make_float4(acc[i][0], acc[i][1], acc[i][2], acc[i][3]);
      float4 v1 = make_float4(acc[i][4], acc[i][5], acc[i][6], acc[i][7]);
      *reinterpret_cast<float4*>(C + (size_t)gr * N + bn + tx * 8) = v0;
      *reinterpret_cast<float4*>(C + (size_t)gr * N + bn + tx * 8 + 4) = v1;
    }
  }
}

// ---------------- MFMA bf16 GEMM: C[Mpad,N](bf16) = A[Mpad,K] @ Wt[N,K]^T ----------------
// TA = float  -> reg-stage + cvt (global loads guarded by Mreal, zeros beyond)
// TA = ushort -> global_load_lds direct (A must be padded to Mpad rows)
// LDS XOR-swizzle: physical byte chunk pc holds logical byte chunk pc ^ ((row&3)<<4)
// (involution; applied on global SOURCE for staging and on the frag-read address)
template <typename TA, int K>
__global__ __launch_bounds__(256) void gemm_mfma(
    const TA* __restrict__ A, const unsigned short* __restrict__ Wt,
    unsigned short* __restrict__ C, int Mreal, int N) {
  __shared__ __align__(16) unsigned short lds[2][8192];  // per buf: A[0..4095], B[4096..8191] ([128][32] bf16 each)
  const int tid  = threadIdx.x;
  const int wave = tid >> 6;
  const int lane = tid & 63;
  const int bm = blockIdx.x * 128;
  const int bn = blockIdx.y * 128;
  const int wr = wave >> 1, wc = wave & 1;     // wave sub-tile 64x64
  constexpr int NT = K / 32;

  f32x4 acc[4][4] = {};

  const int rb   = lane & 15;
  const int cofs = ((lane >> 4) ^ (lane & 3)) << 3;   // swizzled k-chunk, ushort offset

  auto stageB = [&](int buf, int kt) {
#pragma unroll
    for (int j = 0; j < 2; ++j) {
      const int o   = (wave * 2 + j) * 1024 + lane * 16;  // physical byte offset in tile
      const int row = o >> 6;
      const int sc  = (o & 63) ^ ((row & 3) << 4);
      const char* g = (const char*)Wt + (size_t)(bn + row) * (K * 2) + kt * 64 + sc;
      // LDS dest: wave-uniform base; HW adds lane*16
      __builtin_amdgcn_global_load_lds(
          (const __attribute__((address_space(1))) void*)g,
          (__attribute__((address_space(3))) void*)&lds[buf][4096 + (wave * 2 + j) * 512],
          16, 0, 0);
    }
  };
  auto stageA = [&](int buf, int kt) {
    if constexpr (sizeof(TA) == 2) {
#pragma unroll
      for (int j = 0; j < 2; ++j) {
        const int o   = (wave * 2 + j) * 1024 + lane * 16;
        const int row = o >> 6;
        const int sc  = (o & 63) ^ ((row & 3) << 4);
        const char* g = (const char*)A + (size_t)(bm + row) * (K * 2) + kt * 64 + sc;
        __builtin_amdgcn_global_load_lds(
            (const __attribute__((address_space(1))) void*)g,
            (__attribute__((address_space(3))) void*)&lds[buf][(wave * 2 + j) * 512],
            16, 0, 0);
      }
    } else {
#pragma unroll
      for (int p = 0; p < 2; ++p) {
        const int o   = p * 4096 + tid * 16;
        const int row = o >> 6;
        const int ke  = ((o & 63) ^ ((row & 3) << 4)) >> 1;  // logical bf16 elem offset (mult of 8)
        const int gr  = bm + row;
        float v[8];
#pragma unroll
        for (int q = 0; q < 8; ++q) v[q] = 0.f;
        if (gr < Mreal) {
          const float* gp = (const float*)A + (size_t)gr * K + kt * 32 + ke;
          float4 u0 = *(const float4*)gp;
          float4 u1 = *(const float4*)(gp + 4);
          v[0] = u0.x; v[1] = u0.y; v[2] = u0.z; v[3] = u0.w;
          v[4] = u1.x; v[5] = u1.y; v[6] = u1.z; v[7] = u1.w;
        }
        bf16x8 pk;
#pragma unroll
        for (int q = 0; q < 8; ++q) pk[q] = (short)f2bf(v[q]);
        *(bf16x8*)&lds[buf][o >> 1] = pk;
      }
    }
  };

  stageA(0, 0); stageB(0, 0);
  for (int t = 0; t < NT; ++t) {
    __syncthreads();                       // drains vmcnt+lgkm of stage(t)
    if (t + 1 < NT) { stageA((t + 1) & 1, t + 1); stageB((t + 1) & 1, t + 1); }
    const int buf = t & 1;
    bf16x8 af[4], bfr[4];
#pragma unroll
    for (int m = 0; m < 4; ++m)
      af[m] = *(const bf16x8*)&lds[buf][(rb + 16 * m + 64 * wr) * 32 + cofs];
#pragma unroll
    for (int n = 0; n < 4; ++n)
      bfr[n] = *(const bf16x8*)&lds[buf][4096 + (rb + 16 * n + 64 * wc) * 32 + cofs];
#pragma unroll
    for (int m = 0; m < 4; ++m)
#pragma unroll
      for (int n = 0; n < 4; ++n)
        acc[m][n] = __builtin_amdgcn_mfma_f32_16x16x32_bf16(af[m], bfr[n], acc[m][n], 0, 0, 0);
  }

  // C/D layout: col = lane&15, row = (lane>>4)*4 + reg   [m89 verified]
  const int ccol = bn + wc * 64 + rb;
  const int crow = bm + wr * 64 + ((lane >> 4) << 2);
#pragma unroll
  for (int m = 0; m < 4; ++m)
#pragma unroll
    for (int n = 0; n < 4; ++n)
#pragma unroll
      for (int r = 0; r < 4; ++r)
        C[(size_t)(crow + 16 * m + r) * N + ccol + 16 * n] = f2bf(acc[m][n][r]);
}

// ---------------- layer-1 aggregation: one wave per (node, head) ----------------
__global__ __launch_bounds__(256) void agg1(
    const unsigned short* __restrict__ xa, const unsigned short* __restrict__ eeA31,
    const float* __restrict__ relA3, const int* __restrict__ rowptr,
    const int* __restrict__ csr, const int* __restrict__ dst,
    const int* __restrict__ etnh, const float* __restrict__ a2,
    unsigned short* __restrict__ x1) {
  int w = blockIdx.x * 4 + (threadIdx.x >> 6);
  int n = w >> 1, h = w & 1;
  if (n >= N_NODES) return;
  int l = threadIdx.x & 63;
  float w2a = a2[h * 128 + l];
  float w2b = a2[h * 128 + 64 + l];
  const unsigned short* xan = xa + (size_t)n * 512 + h * 256;
  float s0 = bf2f(xan[l]), s1 = bf2f(xan[64 + l]);
  float acc0 = 0.f, acc1 = 0.f, rs = 0.f;
  int p0 = rowptr[n], p1 = rowptr[n + 1];
  for (int p = p0; p < p1; ++p) {
    int e = csr[p];
    int d = dst[e];
    const unsigned short* xad = xa + (size_t)d * 512 + h * 256 + 128;
    float m0 = s0 + bf2f(xad[l]);
    float m1 = s1 + bf2f(xad[64 + l]);
    if (e < E1) {
      const unsigned short* ee = eeA31 + (size_t)e * 256 + h * 128;
      m0 += bf2f(ee[l]); m1 += bf2f(ee[64 + l]);
    } else {
      int k = e - E1;
      int t0 = etnh[2 * k], t1 = etnh[2 * k + 1];
      const float* r0 = relA3 + t0 * 256 + h * 128;
      const float* r1 = relA3 + t1 * 256 + h * 128;
      m0 += r0[l] + r1[l];
      m1 += r0[64 + l] + r1[64 + l];
    }
    float dot = m0 * w2a + m1 * w2b;
#pragma unroll
    for (int off = 32; off; off >>= 1) dot += __shfl_xor(dot, off);
    float lk = dot > 0.f ? dot : ALPHA_F * dot;
    float ev = __expf(-lk);
    acc0 = fmaf(ev, m0, acc0);
    acc1 = fmaf(ev, m1, acc1);
    rs += ev;
  }
  if (rs == 0.f) rs = 1e-12f;
  float inv = 1.f / rs;
  float h0 = acc0 * inv, h1 = acc1 * inv;
  h0 = h0 > 0.f ? h0 : (__expf(h0) - 1.f);  // elu (concat=True)
  h1 = h1 > 0.f ? h1 : (__expf(h1) - 1.f);
  x1[(size_t)n * 256 + h * 128 + l] = f2bf(h0);
  x1[(size_t)n * 256 + h * 128 + 64 + l] = f2bf(h1);
}

// ---------------- layer-2 aggregation: one wave per node ----------------
__global__ __launch_bounds__(256) void agg2(
    const unsigned short* __restrict__ x1a, const float* __restrict__ rel2,
    const int* __restrict__ rowptr, const int* __restrict__ csr,
    const int* __restrict__ dst, const int* __restrict__ etype,
    const int* __restrict__ etnh, const float* __restrict__ a2o,
    float* __restrict__ out) {
  int n = blockIdx.x * 4 + (threadIdx.x >> 6);
  if (n >= N_NODES) return;
  int l = threadIdx.x & 63;
  float w2[4], s[4], acc[4] = {0.f, 0.f, 0.f, 0.f};
#pragma unroll
  for (int j = 0; j < 4; ++j) {
    w2[j] = a2o[j * 64 + l];
    s[j] = bf2f(x1a[(size_t)n * 512 + j * 64 + l]);
  }
  float rs = 0.f;
  int p0 = rowptr[n], p1 = rowptr[n + 1];
  for (int p = p0; p < p1; ++p) {
    int e = csr[p];
    int d = dst[e];
    const unsigned short* xd = x1a + (size_t)d * 512 + 256;
    float m[4];
    if (e < E1) {
      int t = etype[e];
      const float* r = rel2 + t * 256;
#pragma unroll
      for (int j = 0; j < 4; ++j) m[j] = s[j] + bf2f(xd[j * 64 + l]) + r[j * 64 + l];
    } else {
      int k = e - E1;
      int t0 = etnh[2 * k], t1 = etnh[2 * k + 1];
      const float* r0 = rel2 + t0 * 256;
      const float* r1 = rel2 + t1 * 256;
#pragma unroll
      for (int j = 0; j < 4; ++j) m[j] = s[j] + bf2f(xd[j * 64 + l]) + r0[j * 64 + l] + r1[j * 64 + l];
    }
    float dot = 0.f;
#pragma unroll
    for (int j = 0; j < 4; ++j) dot = fmaf(m[j], w2[j], dot);
#pragma unroll
    for (int off = 32; off; off >>= 1) dot += __shfl_xor(dot, off);
    float lk = dot > 0.f ? dot : ALPHA_F * dot;
    float ev = __expf(-lk);
#pragma unroll
    for (int j = 0; j < 4; ++j) acc[j] = fmaf(ev, m[j], acc[j]);
    rs += ev;
  }
  if (rs == 0.f) rs = 1e-12f;
  float inv = 1.f / rs;
#pragma unroll
  for (int j = 0; j < 4; ++j) {
    float hv = acc[j] * inv;
    hv = hv > 0.f ? hv : (__expf(hv) - 1.f);  // final elu
    out[(size_t)n * 256 + j * 64 + l] = hv;
  }
}

// ---------------- launch ----------------
extern "C" void kernel_launch(void* const* d_in, const int* in_sizes, int n_in,
                              void* d_out, int out_size, void* d_ws, size_t ws_size,
                              hipStream_t stream) {
  const float* x    = (const float*)d_in[0];   // [50000,128]
  const float* rel  = (const float*)d_in[1];   // [500,128]
  const float* eemb = (const float*)d_in[2];   // [150000,128]
  const int*   el   = (const int*)d_in[3];     // [2,150000]
  const int*   et   = (const int*)d_in[4];     // [150000]
  const int*   elnh = (const int*)d_in[5];     // [2,30000]
  const int*   etnh = (const int*)d_in[6];     // [30000,2]
  const float* a    = (const float*)d_in[7];   // [2,128,384]
  const float* a2   = (const float*)d_in[8];   // [2,128]
  const float* W    = (const float*)d_in[9];   // [128,256]
  const float* aout = (const float*)d_in[10];  // [256,768]
  const float* a2o  = (const float*)d_in[11];  // [256]

  char* ws = (char*)d_ws;
  size_t cur = 0;
  auto alloc = [&](size_t bytes) {
    size_t o = cur;
    cur = (cur + bytes + 511) & ~(size_t)511;
    return o;
  };
  int* src     = (int*)(ws + alloc((size_t)ETOT * 4));
  int* dstv    = (int*)(ws + alloc((size_t)ETOT * 4));
  int* rowptr  = (int*)(ws + alloc((size_t)(N_NODES + 1) * 4));
  int* pos     = (int*)(ws + alloc((size_t)N_NODES * 4));
  int* csr     = (int*)(ws + alloc((size_t)ETOT * 4));
  int* bsum    = (int*)(ws + alloc((size_t)64 * 4));
  float* weea3f = (float*)(ws + alloc((size_t)256 * 128 * 4));
  float* wtw    = (float*)(ws + alloc((size_t)256 * 128 * 4));
  float* wa3o   = (float*)(ws + alloc((size_t)256 * 256 * 4));
  unsigned short* wxa_bf   = (unsigned short*)(ws + alloc((size_t)512 * 128 * 2));
  unsigned short* weea3_bf = (unsigned short*)(ws + alloc((size_t)256 * 128 * 2));
  unsigned short* wx1a_bf  = (unsigned short*)(ws + alloc((size_t)512 * 256 * 2));
  float* relA3 = (float*)(ws + alloc((size_t)NRELC * 256 * 4));
  float* rel2  = (float*)(ws + alloc((size_t)NRELC * 256 * 4));
  unsigned short* x1B = (unsigned short*)(ws + alloc((size_t)MP1 * 256 * 2));  // 25.6MB (padded)
  unsigned short* xaB = (unsigned short*)(ws + alloc((size_t)MP1 * 512 * 2));  // 51.2MB (padded; reused as x1a)
  unsigned short* eeB = (unsigned short*)(ws + alloc((size_t)MP2 * 256 * 2));  // 76.8MB (padded)
  (void)ws_size; (void)in_sizes; (void)n_in; (void)out_size;

  float* out_x    = (float*)d_out;                       // [50000,256]
  float* out_rel1 = out_x + (size_t)N_NODES * 256;       // [500,256]

  // CSR build (hierarchical scan)
  zero_int<<<(N_NODES + 255) / 256, 256, 0, stream>>>(pos, N_NODES);
  build_count<<<(ETOT + 255) / 256, 256, 0, stream>>>(el, elnh, src, dstv, pos);
  block_scan<<<NBSCAN, 256, 0, stream>>>(pos, rowptr, bsum);
  scan_blocksums<<<1, 64, 0, stream>>>(bsum, rowptr);
  add_offsets<<<(N_NODES + 255) / 256, 256, 0, stream>>>(rowptr, bsum, pos);
  fill_csr<<<(ETOT + 255) / 256, 256, 0, stream>>>(src, pos, csr);

  // weight packs (fused)
  pack_all<<<(PK_TOT + 255) / 256, 256, 0, stream>>>(a, W, aout, weea3f, wtw, wa3o,
                                                     wxa_bf, weea3_bf, wx1a_bf);

  // layer-1 transforms (MFMA)
  gemm_mfma<float, 128><<<dim3(MP1 / 128, 4), 256, 0, stream>>>(x, wxa_bf, xaB, N_NODES, 512);
  gemm_mfma<float, 128><<<dim3(MP2 / 128, 2), 256, 0, stream>>>(eemb, weea3_bf, eeB, E1, 256);
  gemm_bt_f32<<<dim3((NRELC + 127) / 128, 2), 256, 0, stream>>>(rel, weea3f, relA3, NRELC, 256, 128);

  // layer-1 aggregation -> x1
  agg1<<<(N_NODES * 2 + 3) / 4, 256, 0, stream>>>(xaB, eeB, relA3, rowptr, csr, dstv, etnh, a2, x1B);

  // out_relation_1 = rel @ W (direct to output), rel2 table
  gemm_bt_f32<<<dim3((NRELC + 127) / 128, 2), 256, 0, stream>>>(rel, wtw, out_rel1, NRELC, 256, 128);
  gemm_bt_f32<<<dim3((NRELC + 127) / 128, 2), 256, 0, stream>>>(out_rel1, wa3o, rel2, NRELC, 256, 256);

  // layer-2 transform (MFMA, A = x1B bf16 padded)
  gemm_mfma<unsigned short, 256><<<dim3(MP1 / 128, 4), 256, 0, stream>>>(x1B, wx1a_bf, xaB, MP1, 512);

  // layer-2 aggregation -> final x
  agg2<<<(N_NODES + 3) / 4, 256, 0, stream>>>(xaB, rel2, rowptr, csr, dstv, et, etnh, a2o, out_x);
}